// Round 4
// baseline (719.053 us; speedup 1.0000x reference)
//
#include <hip/hip_runtime.h>
#include <hip/hip_bf16.h>

typedef __hip_bfloat16 bf16;

// dtype-flexible scalar load: bf16 or f32 element i
__device__ __forceinline__ float ldf(const void* p, long i, bool isb) {
    return isb ? __bfloat162float(((const bf16*)p)[i]) : ((const float*)p)[i];
}

// order-preserving float <-> uint mapping for atomicMax-based segment max
__device__ __forceinline__ unsigned f2sort(float f) {
    unsigned u = __float_as_uint(f);
    return (u & 0x80000000u) ? ~u : (u | 0x80000000u);
}
__device__ __forceinline__ float sort2f(unsigned u) {
    return (u & 0x80000000u) ? __uint_as_float(u & 0x7FFFFFFFu)
                             : __uint_as_float(~u);
}

// Per-tensor input dtype detection (proven across rounds 2/3: selects f32).
// flags[0]: x bf16?  flags[1]: edge_attr bf16?  flags[2]: weights bf16?  flags[3]: idx int64?
__global__ void detect_kernel(const unsigned short* __restrict__ x16,
                              const unsigned short* __restrict__ ea16,
                              const unsigned short* __restrict__ we16,
                              const int* __restrict__ ei,
                              unsigned* __restrict__ flags)
{
    __shared__ int cnt[4];
    int t = threadIdx.x; // 256 threads
    if (t < 4) cnt[t] = 0;
    __syncthreads();
    auto sane = [](unsigned short u) { int ex = (u >> 7) & 0xFF; return ex >= 97 && ex <= 157; };
    if (sane(x16[t]))  atomicAdd(&cnt[0], 1);
    if (sane(ea16[t])) atomicAdd(&cnt[1], 1);
    if (t < 32 && sane(we16[t])) atomicAdd(&cnt[2], 1);
    if (t < 32 && ei[2 * t + 1] == 0) atomicAdd(&cnt[3], 1);
    __syncthreads();
    if (t == 0) {
        flags[0] = (cnt[0] >= 240) ? 1u : 0u;
        flags[1] = (cnt[1] >= 240) ? 1u : 0u;
        flags[2] = (cnt[2] >= 29) ? 1u : 0u;
        flags[3] = (cnt[3] == 32) ? 1u : 0u;
    }
}

// Shared per-edge logit computation (exact f32, matching the np reference).
__device__ __forceinline__ void compute_pp(const void* __restrict__ x,
                                           const int* __restrict__ ei,
                                           const void* __restrict__ ea,
                                           const float* __restrict__ wn,
                                           const float* __restrict__ we,
                                           bool fx, bool fe, bool i64,
                                           int e, int E,
                                           float& pp0, float& pp1, int& s, int& d)
{
    size_t sw = i64 ? (size_t)2 * e : (size_t)e;
    size_t dw = i64 ? ((size_t)2 * E + 2 * (size_t)e) : ((size_t)E + e);
    s = ei[sw]; d = ei[dw];
    float xs = ldf(x, s, fx), xd = ldf(x, d, fx);
    float l0 = xs * wn[0] + xd * wn[2];
    float l1 = xs * wn[1] + xd * wn[3];
    if (fe) {
        const uint4* p = (const uint4*)((const bf16*)ea + (size_t)e * 16);
        uint4 a = p[0], b = p[1];
        unsigned w[8] = {a.x, a.y, a.z, a.w, b.x, b.y, b.z, b.w};
#pragma unroll
        for (int k = 0; k < 8; ++k) {
            float lo = __uint_as_float(w[k] << 16);          // elem 2k
            float hi = __uint_as_float(w[k] & 0xFFFF0000u);  // elem 2k+1
            l0 += lo * we[4 * k + 0] + hi * we[4 * k + 2];
            l1 += lo * we[4 * k + 1] + hi * we[4 * k + 3];
        }
    } else {
        const float4* p = (const float4*)((const float*)ea + (size_t)e * 16);
#pragma unroll
        for (int q = 0; q < 4; ++q) {
            float4 v = p[q];
            l0 += v.x * we[8 * q + 0] + v.y * we[8 * q + 2] +
                  v.z * we[8 * q + 4] + v.w * we[8 * q + 6];
            l1 += v.x * we[8 * q + 1] + v.y * we[8 * q + 3] +
                  v.z * we[8 * q + 5] + v.w * we[8 * q + 7];
        }
    }
    pp0 = l0 >= 0.f ? l0 : 0.2f * l0;  // leaky_relu(., 0.2)
    pp1 = l1 >= 0.f ? l1 : 0.2f * l1;
}

#define STAGE_WEIGHTS()                                              \
    __shared__ float wn[4];                                          \
    __shared__ float we[32];                                         \
    const bool fx = flags[0] != 0, fe = flags[1] != 0;               \
    const bool fw = flags[2] != 0, i64 = flags[3] != 0;              \
    {                                                                \
        int tt = threadIdx.x;                                        \
        if (tt < 4)  wn[tt] = ldf(W_node, tt, fw);                   \
        if (tt < 32) we[tt] = ldf(W_edge, tt, fw);                   \
    }                                                                \
    __syncthreads();

// Pass 1: pair_pred (f32 out), optional f32 score stash, segment max
__global__ void pass1_kernel(const void* __restrict__ x, const int* __restrict__ ei,
                             const void* __restrict__ ea,
                             const void* __restrict__ W_node, const void* __restrict__ W_edge,
                             float2* __restrict__ out_pp, float* __restrict__ score,
                             unsigned* __restrict__ msort,
                             const unsigned* __restrict__ flags, int use_score, int E)
{
    STAGE_WEIGHTS();
    int e = blockIdx.x * blockDim.x + threadIdx.x;
    if (e >= E) return;
    float pp0, pp1; int s, d;
    compute_pp(x, ei, ea, wn, we, fx, fe, i64, e, E, pp0, pp1, s, d);
    out_pp[e] = make_float2(pp0, pp1);
    float sc = pp0 - pp1;
    if (use_score) score[e] = sc;
    atomicMax(msort + d, f2sort(sc));
}

// Pass 2: ex = exp(score - m[dst]); denom += ex  (recomputes score if no scratch)
__global__ void pass2_kernel(const void* __restrict__ x, const int* __restrict__ ei,
                             const void* __restrict__ ea,
                             const void* __restrict__ W_node, const void* __restrict__ W_edge,
                             const unsigned* __restrict__ msort,
                             float* __restrict__ score, float* __restrict__ denom,
                             const unsigned* __restrict__ flags, int use_score, int E)
{
    STAGE_WEIGHTS();
    int e = blockIdx.x * blockDim.x + threadIdx.x;
    if (e >= E) return;
    float sc; int d;
    if (use_score) {
        sc = score[e];
        size_t dw = i64 ? ((size_t)2 * E + 2 * (size_t)e) : ((size_t)E + e);
        d = ei[dw];
    } else {
        float pp0, pp1; int s;
        compute_pp(x, ei, ea, wn, we, fx, fe, i64, e, E, pp0, pp1, s, d);
        sc = pp0 - pp1;
    }
    float ex = expf(sc - sort2f(msort[d]));
    if (use_score) score[e] = ex;
    atomicAdd(denom + d, ex);
}

// Pass 3: attn -> f32 out; out_acc[dst] += attn * x[src] * W00
__global__ void pass3_kernel(const void* __restrict__ x, const int* __restrict__ ei,
                             const void* __restrict__ ea,
                             const void* __restrict__ W_node, const void* __restrict__ W_edge,
                             const void* __restrict__ W,
                             const unsigned* __restrict__ msort,
                             const float* __restrict__ score, const float* __restrict__ denom,
                             float* __restrict__ out_attn, float* __restrict__ out_acc,
                             const unsigned* __restrict__ flags, int use_score, int E)
{
    STAGE_WEIGHTS();
    int e = blockIdx.x * blockDim.x + threadIdx.x;
    if (e >= E) return;
    float ex; int s, d;
    if (use_score) {
        size_t sw = i64 ? (size_t)2 * e : (size_t)e;
        size_t dw = i64 ? ((size_t)2 * E + 2 * (size_t)e) : ((size_t)E + e);
        s = ei[sw]; d = ei[dw];
        ex = score[e];
    } else {
        float pp0, pp1;
        compute_pp(x, ei, ea, wn, we, fx, fe, i64, e, E, pp0, pp1, s, d);
        ex = expf((pp0 - pp1) - sort2f(msort[d]));
    }
    float a = ex / (denom[d] + 1e-16f);
    out_attn[e] = a;
    float w0 = ldf(W, 0, fw);
    atomicAdd(out_acc + d, a * ldf(x, s, fx) * w0);
}

// Pass 4: fp32 accumulator -> f32 node output
__global__ void finalize_kernel(const float* __restrict__ out_acc,
                                float* __restrict__ out_node, int N)
{
    int n = blockIdx.x * blockDim.x + threadIdx.x;
    if (n >= N) return;
    out_node[n] = out_acc[n];
}

extern "C" void kernel_launch(void* const* d_in, const int* in_sizes, int n_in,
                              void* d_out, int out_size, void* d_ws, size_t ws_size,
                              hipStream_t stream)
{
    const void* x      = d_in[0];
    const int*  ei     = (const int*)d_in[1];
    const void* ea     = d_in[2];
    const void* W      = d_in[3];
    const void* W_node = d_in[4];
    const void* W_edge = d_in[5];

    const int N = in_sizes[0];       // x is [N,1]
    const int E = in_sizes[1] / 2;   // edge_index is [2,E]

    // outputs (all f32, reference output dtype): out[N] ++ attn[E] ++ pair_pred[2E]
    float*  out_node = (float*)d_out;
    float*  out_attn = out_node + N;
    float2* out_pp   = (float2*)(out_attn + E);

    // ws layout: flags[4] u32 | msort[N] u32 | denom[N] f32 | outacc[N] f32 | [score[E] f32]
    unsigned* flags  = (unsigned*)d_ws;
    unsigned* msort  = flags + 4;
    float*    denom  = (float*)(msort + N);
    float*    outacc = denom + N;
    float*    score  = outacc + N;

    // Only use the E-sized f32 score scratch if the workspace actually fits it.
    const size_t need_full = 16 + (size_t)3 * N * 4 + (size_t)E * 4;
    const int use_score = (ws_size >= need_full) ? 1 : 0;

    hipMemsetAsync(msort, 0, (size_t)3 * N * sizeof(float), stream);

    const int blk = 256;
    const int gE = (E + blk - 1) / blk;
    const int gN = (N + blk - 1) / blk;

    detect_kernel<<<1, 256, 0, stream>>>((const unsigned short*)x,
                                         (const unsigned short*)ea,
                                         (const unsigned short*)W_edge, ei, flags);
    pass1_kernel<<<gE, blk, 0, stream>>>(x, ei, ea, W_node, W_edge,
                                         out_pp, score, msort, flags, use_score, E);
    pass2_kernel<<<gE, blk, 0, stream>>>(x, ei, ea, W_node, W_edge,
                                         msort, score, denom, flags, use_score, E);
    pass3_kernel<<<gE, blk, 0, stream>>>(x, ei, ea, W_node, W_edge, W,
                                         msort, score, denom, out_attn, outacc,
                                         flags, use_score, E);
    finalize_kernel<<<gN, blk, 0, stream>>>(outacc, out_node, N);
}

// Round 5
// 577.306 us; speedup vs baseline: 1.2455x; 1.2455x over previous
//
#include <hip/hip_runtime.h>
#include <hip/hip_bf16.h>

typedef __hip_bfloat16 bf16;

// dtype-flexible scalar load: bf16 or f32 element i
__device__ __forceinline__ float ldf(const void* p, long i, bool isb) {
    return isb ? __bfloat162float(((const bf16*)p)[i]) : ((const float*)p)[i];
}

// HW fp32 atomic (global_atomic_add_f32) — avoids HIP's default CAS retry loop.
__device__ __forceinline__ void atomAdd(float* p, float v) {
    unsafeAtomicAdd(p, v);
}

// Per-tensor input dtype detection (rounds 2-4: selects f32/i32; kept for robustness).
// flags[0]: x bf16?  flags[1]: edge_attr bf16?  flags[2]: weights bf16?  flags[3]: idx int64?
__global__ void detect_kernel(const unsigned short* __restrict__ x16,
                              const unsigned short* __restrict__ ea16,
                              const unsigned short* __restrict__ we16,
                              const int* __restrict__ ei,
                              unsigned* __restrict__ flags)
{
    __shared__ int cnt[4];
    int t = threadIdx.x; // 256 threads
    if (t < 4) cnt[t] = 0;
    __syncthreads();
    auto sane = [](unsigned short u) { int ex = (u >> 7) & 0xFF; return ex >= 97 && ex <= 157; };
    if (sane(x16[t]))  atomicAdd(&cnt[0], 1);
    if (sane(ea16[t])) atomicAdd(&cnt[1], 1);
    if (t < 32 && sane(we16[t])) atomicAdd(&cnt[2], 1);
    if (t < 32 && ei[2 * t + 1] == 0) atomicAdd(&cnt[3], 1);
    __syncthreads();
    if (t == 0) {
        flags[0] = (cnt[0] >= 240) ? 1u : 0u;
        flags[1] = (cnt[1] >= 240) ? 1u : 0u;
        flags[2] = (cnt[2] >= 29) ? 1u : 0u;
        flags[3] = (cnt[3] == 32) ? 1u : 0u;
    }
}

// Pass A (single edge pass with atomics):
//   pair_pred -> d_out (f32), ex=exp(score) -> score ws,
//   rep[r][2d] += ex (denom), rep[r][2d+1] += ex*x[src] (numerator), r = blockIdx&mask.
// No max-subtraction: softmax is shift-invariant; scores bounded (clamped 80).
__global__ void passA_kernel(const void* __restrict__ x, const int* __restrict__ ei,
                             const void* __restrict__ ea,
                             const void* __restrict__ W_node, const void* __restrict__ W_edge,
                             float2* __restrict__ out_pp, float* __restrict__ score,
                             float* __restrict__ rep,
                             const unsigned* __restrict__ flags,
                             int E, int twoN, int rmask)
{
    __shared__ float wn[4];
    __shared__ float we[32];
    const bool fx = flags[0] != 0, fe = flags[1] != 0;
    const bool fw = flags[2] != 0, i64 = flags[3] != 0;
    {
        int tt = threadIdx.x;
        if (tt < 4)  wn[tt] = ldf(W_node, tt, fw);
        if (tt < 32) we[tt] = ldf(W_edge, tt, fw);
    }
    __syncthreads();

    int e = blockIdx.x * blockDim.x + threadIdx.x;
    if (e >= E) return;

    size_t sw = i64 ? (size_t)2 * e : (size_t)e;
    size_t dw = i64 ? ((size_t)2 * E + 2 * (size_t)e) : ((size_t)E + e);
    int s = ei[sw], d = ei[dw];

    float xs = ldf(x, s, fx), xd = ldf(x, d, fx);
    float l0 = xs * wn[0] + xd * wn[2];
    float l1 = xs * wn[1] + xd * wn[3];

    if (fe) {
        const uint4* p = (const uint4*)((const bf16*)ea + (size_t)e * 16);
        uint4 a = p[0], b = p[1];
        unsigned w[8] = {a.x, a.y, a.z, a.w, b.x, b.y, b.z, b.w};
#pragma unroll
        for (int k = 0; k < 8; ++k) {
            float lo = __uint_as_float(w[k] << 16);
            float hi = __uint_as_float(w[k] & 0xFFFF0000u);
            l0 += lo * we[4 * k + 0] + hi * we[4 * k + 2];
            l1 += lo * we[4 * k + 1] + hi * we[4 * k + 3];
        }
    } else {
        const float4* p = (const float4*)((const float*)ea + (size_t)e * 16);
#pragma unroll
        for (int q = 0; q < 4; ++q) {
            float4 v = p[q];
            l0 += v.x * we[8 * q + 0] + v.y * we[8 * q + 2] +
                  v.z * we[8 * q + 4] + v.w * we[8 * q + 6];
            l1 += v.x * we[8 * q + 1] + v.y * we[8 * q + 3] +
                  v.z * we[8 * q + 5] + v.w * we[8 * q + 7];
        }
    }

    float pp0 = l0 >= 0.f ? l0 : 0.2f * l0;  // leaky_relu(., 0.2)
    float pp1 = l1 >= 0.f ? l1 : 0.2f * l1;
    out_pp[e] = make_float2(pp0, pp1);

    float sc = fminf(pp0 - pp1, 80.f);   // clamp only guards f32 exp overflow
    float ex = __expf(sc) == 0.f ? expf(sc) : expf(sc); // keep precise expf
    score[e] = ex;

    float* myrep = rep + (size_t)(blockIdx.x & rmask) * twoN;
    atomAdd(myrep + 2 * d,     ex);        // denom
    atomAdd(myrep + 2 * d + 1, ex * xs);   // numerator (x[src]); W applied in reduce
}

// Reduce replicas -> denom_tot (for passB) and node output directly.
__global__ void reduce_kernel(const float* __restrict__ rep,
                              float* __restrict__ denom_tot,
                              float* __restrict__ out_node,
                              const void* __restrict__ W,
                              const unsigned* __restrict__ flags,
                              int N, int twoN, int R)
{
    int n = blockIdx.x * blockDim.x + threadIdx.x;
    if (n >= N) return;
    const bool fw = flags[2] != 0;
    float den = 0.f, num = 0.f;
    for (int r = 0; r < R; ++r) {
        den += rep[(size_t)r * twoN + 2 * n];
        num += rep[(size_t)r * twoN + 2 * n + 1];
    }
    denom_tot[n] = den;
    float w0 = ldf(W, 0, fw);
    out_node[n] = w0 * num / (den + 1e-16f);
}

// Pass B (atomic-free): attn = ex / (denom_tot[dst] + 1e-16)
__global__ void passB_kernel(const int* __restrict__ ei,
                             const float* __restrict__ score,
                             const float* __restrict__ denom_tot,
                             float* __restrict__ out_attn,
                             const unsigned* __restrict__ flags, int E)
{
    int e = blockIdx.x * blockDim.x + threadIdx.x;
    if (e >= E) return;
    const bool i64 = flags[3] != 0;
    size_t dw = i64 ? ((size_t)2 * E + 2 * (size_t)e) : ((size_t)E + e);
    int d = ei[dw];
    out_attn[e] = score[e] / (denom_tot[d] + 1e-16f);
}

extern "C" void kernel_launch(void* const* d_in, const int* in_sizes, int n_in,
                              void* d_out, int out_size, void* d_ws, size_t ws_size,
                              hipStream_t stream)
{
    const void* x      = d_in[0];
    const int*  ei     = (const int*)d_in[1];
    const void* ea     = d_in[2];
    const void* W      = d_in[3];
    const void* W_node = d_in[4];
    const void* W_edge = d_in[5];

    const int N = in_sizes[0];       // x is [N,1]
    const int E = in_sizes[1] / 2;   // edge_index is [2,E]
    const int twoN = 2 * N;

    // outputs (all f32): out[N] ++ attn[E] ++ pair_pred[2E]
    float*  out_node = (float*)d_out;
    float*  out_attn = out_node + N;
    float2* out_pp   = (float2*)(out_attn + E);

    // Pick the largest replica count whose footprint fits d_ws.
    // need(R) = flags(16B) + rep(R*2N f32) + denom_tot(N f32) + score(E f32)
    int R = 1;
    for (int cand = 8; cand > 1; cand >>= 1) {
        size_t need = 16 + (size_t)cand * twoN * 4 + (size_t)N * 4 + (size_t)E * 4;
        if (ws_size >= need) { R = cand; break; }
    }
    const int rmask = R - 1;

    // ws layout: flags[4] u32 | rep[R*2N] f32 | denom_tot[N] f32 | score[E] f32
    unsigned* flags     = (unsigned*)d_ws;
    float*    rep       = (float*)(flags + 4);
    float*    denom_tot = rep + (size_t)R * twoN;
    float*    score     = denom_tot + N;

    hipMemsetAsync(rep, 0, (size_t)R * twoN * sizeof(float), stream);

    const int blk = 256;
    const int gE = (E + blk - 1) / blk;
    const int gN = (N + blk - 1) / blk;

    detect_kernel<<<1, 256, 0, stream>>>((const unsigned short*)x,
                                         (const unsigned short*)ea,
                                         (const unsigned short*)W_edge, ei, flags);
    passA_kernel<<<gE, blk, 0, stream>>>(x, ei, ea, W_node, W_edge,
                                         out_pp, score, rep, flags, E, twoN, rmask);
    reduce_kernel<<<gN, blk, 0, stream>>>(rep, denom_tot, out_node, W, flags, N, twoN, R);
    passB_kernel<<<gE, blk, 0, stream>>>(ei, score, denom_tot, out_attn, flags, E);
}